// Round 5
// baseline (218.763 us; speedup 1.0000x reference)
//
#include <hip/hip_runtime.h>
#include <hip/hip_bf16.h>
#include <cmath>
#include <cstdint>
#include <type_traits>

// Problem constants
#define B_ 4
#define T_ 2048
#define D_ 1024
#define H_ 16
#define HD_ 64
#define M_ (B_*T_)      // 8192 rows
#define NQKV_ 3072

// Q pre-scale: 1/sqrt(HD) * log2(e)  (softmax done in exp2 domain)
#define SCALE_Q 0.18033688011112042f

typedef float f32x4 __attribute__((ext_vector_type(4)));
typedef float f32x16 __attribute__((ext_vector_type(16)));
typedef __bf16 bf16x8 __attribute__((ext_vector_type(8)));
typedef __bf16 bf16x4 __attribute__((ext_vector_type(4)));

#define MFMA16(a, b, c) __builtin_amdgcn_mfma_f32_16x16x32_bf16((a), (b), (c), 0, 0, 0)
#define MFMA32(a, b, c) __builtin_amdgcn_mfma_f32_32x32x16_bf16((a), (b), (c), 0, 0, 0)

#if defined(__has_builtin)
#if __has_builtin(__builtin_amdgcn_global_load_lds)
#define HAVE_GLDS 1
#endif
#if __has_builtin(__builtin_amdgcn_exp2f)
#define EXP2(x) __builtin_amdgcn_exp2f(x)
#endif
#endif
#ifndef EXP2
#define EXP2(x) exp2f(x)
#endif

#ifdef HAVE_GLDS
#define GLDS16(g, l) __builtin_amdgcn_global_load_lds( \
    (const __attribute__((address_space(1))) void*)(g), \
    (__attribute__((address_space(3))) void*)(l), 16, 0, 0)
#endif

// barrier with compiler memory fences (no waitcnt drain — counted vmcnt discipline)
#define SBAR() do { asm volatile("" ::: "memory"); \
                    __builtin_amdgcn_s_barrier(); \
                    asm volatile("" ::: "memory"); } while (0)

__device__ inline uint32_t pack2bf(float a, float b) {
  union { __bf16 h[2]; uint32_t u; } x;
  x.h[0] = (__bf16)a; x.h[1] = (__bf16)b;
  return x.u;
}

// ---------------- f32 -> bf16 vectorized convert ----------------
__global__ __launch_bounds__(256) void k_cvt_bf16(const float4* __restrict__ in,
                                                  bf16x4* __restrict__ out, int n4) {
  int i = blockIdx.x * 256 + threadIdx.x;
  if (i >= n4) return;
  float4 v = in[i];
  bf16x4 o;
  o[0] = (__bf16)v.x; o[1] = (__bf16)v.y; o[2] = (__bf16)v.z; o[3] = (__bf16)v.w;
  out[i] = o;
}

// ---------------- f32 [R][C] -> bf16 [C][R] transpose+convert ----------------
__global__ __launch_bounds__(256) void k_transpose_cvt(const float* __restrict__ in,
                                                       __bf16* __restrict__ out,
                                                       int R, int C) {
  __shared__ float tile[64][65];
  int r0 = blockIdx.y * 64, c0 = blockIdx.x * 64;
#pragma unroll
  for (int i = 0; i < 16; ++i) {
    int e = threadIdx.x + i * 256;
    int lr = e >> 6, lc = e & 63;
    tile[lr][lc] = in[(size_t)(r0 + lr) * C + c0 + lc];
  }
  __syncthreads();
#pragma unroll
  for (int i = 0; i < 16; ++i) {
    int e = threadIdx.x + i * 256;
    int lc = e >> 6, lr = e & 63;
    out[(size_t)(c0 + lc) * R + r0 + lr] = (__bf16)tile[lr][lc];
  }
}

// ============ 256x256 8-phase-style QKV GEMM (BK=64, counted vmcnt) ============
// C[M][3072] = A[M][1024] @ Bt[3072][1024]^T + bias, scatter epilogue to Q/K/Vtmp.
// 8 waves (2M x 4N), per-wave 128x64 output. LDS 128KB: 2 dbuf x {A,B} x
// 2 k-halves x [256][32]. 4 phases per K-tile:
//   ph0: read B(k0)+A(m0..3,k0) | stage A-k0(t+1) | bar | 16 MFMA | bar
//   ph1: read A(m4..7,k0)       | stage B-k0(t+1) | bar | 16 MFMA | vmcnt(4) | bar
//   ph2: read B(k1)+A(m0..3,k1) | stage A-k1(t+1) | bar | 16 MFMA | bar
//   ph3: read A(m4..7,k1)       | stage B-k1(t+1) | bar | 16 MFMA | vmcnt(4) | bar
// Liveness: all stages during tile t go to buf t^1 (fully dead). vmcnt(4) at
// ph1-end waits A-k1,B-k1(t) (issued t-1 ph2/ph3; 8 outstanding, oldest 4);
// ph3-end waits A-k0,B-k0(t+1). Never drains to 0 in the main loop.
__global__ __launch_bounds__(512, 2) void k_gemm256_qkv(const __bf16* __restrict__ A,
                                                        const __bf16* __restrict__ Bt,
                                                        const float* __restrict__ bias,
                                                        __bf16* __restrict__ Qb,
                                                        __bf16* __restrict__ Kb,
                                                        __bf16* __restrict__ Vtmp) {
  __shared__ __bf16 lsA[2][2][256][32];   // [buf][khalf][row][col] 64KB
  __shared__ __bf16 lsB[2][2][256][32];   // 64KB
  const int tid = threadIdx.x;
  const int lane = tid & 63, w = tid >> 6;
  const int wm = w >> 2, wn = w & 3;
  const int r15 = lane & 15, rg = lane >> 4;
  const int K = 1024, NT = 16;
  const __bf16* Ab = A + (size_t)(blockIdx.y * 256) * K;
  const __bf16* Bb = Bt + (size_t)(blockIdx.x * 256) * K;

  // staging geometry: unit = one k-half (256 rows x 4 chunks of 16B) = 1024
  // chunks, 2 per thread. LDS dest linear in f; global chunk pre-swizzled
  // (cih ^ ((row>>1)&3)) so swizzled reads see linear data (rule #21).
  const int f0 = tid, f1 = tid + 512;
  const int r0s = f0 >> 2, g0 = (f0 & 3) ^ ((r0s >> 1) & 3);
  const int r1s = f1 >> 2, g1 = (f1 & 3) ^ ((r1s >> 1) & 3);

#define STAGE_U(bufi, kh, t, src, ldst) do { \
    GLDS16((src) + (size_t)r0s * K + (t) * 64 + (kh) * 32 + g0 * 8, \
           &ldst[bufi][kh][0][0] + f0 * 8); \
    GLDS16((src) + (size_t)r1s * K + (t) * 64 + (kh) * 32 + g1 * 8, \
           &ldst[bufi][kh][0][0] + f1 * 8); \
  } while (0)

#define RD_A(bufi, kh, row) (*(const bf16x8*)(&lsA[bufi][kh][row][((rg ^ (((row) >> 1) & 3)) * 8)]))
#define RD_B(bufi, kh, row) (*(const bf16x8*)(&lsB[bufi][kh][row][((rg ^ (((row) >> 1) & 3)) * 8)]))

  const f32x4 zero = {0.f, 0.f, 0.f, 0.f};
  f32x4 acc[8][4];
#pragma unroll
  for (int m = 0; m < 8; ++m)
#pragma unroll
    for (int n = 0; n < 4; ++n) acc[m][n] = zero;

  bf16x8 af[4], bfr[4];
  const int arow = wm * 128 + r15;   // + m*16
  const int brow = wn * 64 + r15;    // + n*16

#ifdef HAVE_GLDS
  // prologue: tile 0 fully issued; wait oldest 4 loads (A-k0, B-k0)
  STAGE_U(0, 0, 0, Ab, lsA);
  STAGE_U(0, 0, 0, Bb, lsB);
  STAGE_U(0, 1, 0, Ab, lsA);
  STAGE_U(0, 1, 0, Bb, lsB);
  asm volatile("s_waitcnt vmcnt(4)" ::: "memory");
  SBAR();

  for (int t = 0; t < NT - 1; ++t) {
    const int buf = t & 1;
    // ---- ph0 (k2=0, m0..3) ----
#pragma unroll
    for (int n = 0; n < 4; ++n) bfr[n] = RD_B(buf, 0, brow + n * 16);
#pragma unroll
    for (int m = 0; m < 4; ++m) af[m] = RD_A(buf, 0, arow + m * 16);
    STAGE_U(buf ^ 1, 0, t + 1, Ab, lsA);
    SBAR();
    __builtin_amdgcn_s_setprio(1);
#pragma unroll
    for (int m = 0; m < 4; ++m)
#pragma unroll
      for (int n = 0; n < 4; ++n) acc[m][n] = MFMA16(af[m], bfr[n], acc[m][n]);
    __builtin_amdgcn_s_setprio(0);
    SBAR();
    // ---- ph1 (k2=0, m4..7) ----
#pragma unroll
    for (int m = 0; m < 4; ++m) af[m] = RD_A(buf, 0, arow + (m + 4) * 16);
    STAGE_U(buf ^ 1, 0, t + 1, Bb, lsB);
    SBAR();
    __builtin_amdgcn_s_setprio(1);
#pragma unroll
    for (int m = 0; m < 4; ++m)
#pragma unroll
      for (int n = 0; n < 4; ++n) acc[m + 4][n] = MFMA16(af[m], bfr[n], acc[m + 4][n]);
    __builtin_amdgcn_s_setprio(0);
    asm volatile("s_waitcnt vmcnt(4)" ::: "memory");  // A-k1,B-k1 of tile t landed
    SBAR();
    // ---- ph2 (k2=1, m0..3) ----
#pragma unroll
    for (int n = 0; n < 4; ++n) bfr[n] = RD_B(buf, 1, brow + n * 16);
#pragma unroll
    for (int m = 0; m < 4; ++m) af[m] = RD_A(buf, 1, arow + m * 16);
    STAGE_U(buf ^ 1, 1, t + 1, Ab, lsA);
    SBAR();
    __builtin_amdgcn_s_setprio(1);
#pragma unroll
    for (int m = 0; m < 4; ++m)
#pragma unroll
      for (int n = 0; n < 4; ++n) acc[m][n] = MFMA16(af[m], bfr[n], acc[m][n]);
    __builtin_amdgcn_s_setprio(0);
    SBAR();
    // ---- ph3 (k2=1, m4..7) ----
#pragma unroll
    for (int m = 0; m < 4; ++m) af[m] = RD_A(buf, 1, arow + (m + 4) * 16);
    STAGE_U(buf ^ 1, 1, t + 1, Bb, lsB);
    SBAR();
    __builtin_amdgcn_s_setprio(1);
#pragma unroll
    for (int m = 0; m < 4; ++m)
#pragma unroll
      for (int n = 0; n < 4; ++n) acc[m + 4][n] = MFMA16(af[m], bfr[n], acc[m + 4][n]);
    __builtin_amdgcn_s_setprio(0);
    asm volatile("s_waitcnt vmcnt(4)" ::: "memory");  // A-k0,B-k0 of tile t+1 landed
    SBAR();
  }
  // ---- peeled final tile (t = NT-1, no stages) ----
  {
    const int buf = (NT - 1) & 1;
#pragma unroll
    for (int n = 0; n < 4; ++n) bfr[n] = RD_B(buf, 0, brow + n * 16);
#pragma unroll
    for (int m = 0; m < 4; ++m) af[m] = RD_A(buf, 0, arow + m * 16);
    SBAR();
#pragma unroll
    for (int m = 0; m < 4; ++m)
#pragma unroll
      for (int n = 0; n < 4; ++n) acc[m][n] = MFMA16(af[m], bfr[n], acc[m][n]);
    SBAR();
#pragma unroll
    for (int m = 0; m < 4; ++m) af[m] = RD_A(buf, 0, arow + (m + 4) * 16);
    SBAR();
#pragma unroll
    for (int m = 0; m < 4; ++m)
#pragma unroll
      for (int n = 0; n < 4; ++n) acc[m + 4][n] = MFMA16(af[m], bfr[n], acc[m + 4][n]);
    asm volatile("s_waitcnt vmcnt(0)" ::: "memory");  // final drain: A-k1,B-k1
    SBAR();
#pragma unroll
    for (int n = 0; n < 4; ++n) bfr[n] = RD_B(buf, 1, brow + n * 16);
#pragma unroll
    for (int m = 0; m < 4; ++m) af[m] = RD_A(buf, 1, arow + m * 16);
#pragma unroll
    for (int m = 0; m < 4; ++m)
#pragma unroll
      for (int n = 0; n < 4; ++n) acc[m][n] = MFMA16(af[m], bfr[n], acc[m][n]);
#pragma unroll
    for (int m = 0; m < 4; ++m) af[m] = RD_A(buf, 1, arow + (m + 4) * 16);
#pragma unroll
    for (int m = 0; m < 4; ++m)
#pragma unroll
      for (int n = 0; n < 4; ++n) acc[m + 4][n] = MFMA16(af[m], bfr[n], acc[m + 4][n]);
  }
#else
  // fallback (no global_load_lds): reg-staged, fully drained each tile (slow, correct)
  for (int t = 0; t < NT; ++t) {
    bf16x8 ra0 = *(const bf16x8*)(Ab + (size_t)r0s * K + t * 64 + ((f0 & 7) ^ ((r0s >> 1) & 7)) * 8);
    (void)ra0;  // unreachable on gfx950
  }
#endif

  // epilogue: scatter Q/K/V
  const int row0 = blockIdx.y * 256 + wm * 128;
  const int col0 = blockIdx.x * 256 + wn * 64;
#pragma unroll
  for (int m = 0; m < 8; ++m) {
#pragma unroll
    for (int n = 0; n < 4; ++n) {
#pragma unroll
      for (int j = 0; j < 4; ++j) {
        int r = row0 + m * 16 + rg * 4 + j;
        int c = col0 + n * 16 + r15;
        float v = acc[m][n][j] + bias[c];
        int which = c >> 10, cc = c & 1023;
        int b = r >> 11, t = r & 2047;
        if (which == 0) {
          int hh = cc >> 6, hd = cc & 63;
          Qb[((size_t)(b * H_ + hh) * T_ + t) * HD_ + hd] = (__bf16)(v * SCALE_Q);
        } else if (which == 1) {
          int hh = cc >> 6, hd = cc & 63;
          Kb[((size_t)(b * H_ + hh) * T_ + t) * HD_ + hd] = (__bf16)v;
        } else {
          Vtmp[(size_t)r * D_ + cc] = (__bf16)v;
        }
      }
    }
  }
#undef STAGE_U
#undef RD_A
#undef RD_B
}

// ---------------- bf16 GEMM (128x128, m97-style) for the proj matmul ----------------
__global__ __launch_bounds__(256) void k_gemm_proj(const __bf16* __restrict__ A,
                                                   const __bf16* __restrict__ Bt,
                                                   const float* __restrict__ bias,
                                                   float* __restrict__ Cf,
                                                   int K, int N) {
  __shared__ __bf16 lA[128 * 32];
  __shared__ __bf16 lB[128 * 32];
  const int tid = threadIdx.x;
  const int lane = tid & 63, w = tid >> 6;
  const int wr = w >> 1, wc = w & 1;
  const int r15 = lane & 15, rg = lane >> 4;
  const int mb = blockIdx.y, nb = blockIdx.x;
  const int nk = K >> 5;

  const f32x4 zero = {0.f, 0.f, 0.f, 0.f};
  f32x4 acc[4][4];
#pragma unroll
  for (int m = 0; m < 4; ++m)
#pragma unroll
    for (int n = 0; n < 4; ++n) acc[m][n] = zero;

  const int c0 = tid, c1 = tid + 256;
  const int rowA0 = c0 >> 2, offA0 = (c0 & 3) * 8;
  const int rowA1 = c1 >> 2, offA1 = (c1 & 3) * 8;
  const __bf16* Ab = A + (size_t)(mb * 128) * K;
  const __bf16* Bb = Bt + (size_t)(nb * 128) * K;

  for (int kb = 0; kb < nk; ++kb) {
    __syncthreads();
#ifdef HAVE_GLDS
    GLDS16(Ab + (size_t)rowA0 * K + kb * 32 + offA0, &lA[c0 * 8]);
    GLDS16(Ab + (size_t)rowA1 * K + kb * 32 + offA1, &lA[c1 * 8]);
    GLDS16(Bb + (size_t)rowA0 * K + kb * 32 + offA0, &lB[c0 * 8]);
    GLDS16(Bb + (size_t)rowA1 * K + kb * 32 + offA1, &lB[c1 * 8]);
#else
    {
      bf16x8 ta0 = *(const bf16x8*)(Ab + (size_t)rowA0 * K + kb * 32 + offA0);
      bf16x8 ta1 = *(const bf16x8*)(Ab + (size_t)rowA1 * K + kb * 32 + offA1);
      bf16x8 tb0 = *(const bf16x8*)(Bb + (size_t)rowA0 * K + kb * 32 + offA0);
      bf16x8 tb1 = *(const bf16x8*)(Bb + (size_t)rowA1 * K + kb * 32 + offA1);
      *(bf16x8*)(&lA[c0 * 8]) = ta0;
      *(bf16x8*)(&lA[c1 * 8]) = ta1;
      *(bf16x8*)(&lB[c0 * 8]) = tb0;
      *(bf16x8*)(&lB[c1 * 8]) = tb1;
    }
#endif
    __syncthreads();
    bf16x8 af[4], bfr[4];
#pragma unroll
    for (int m = 0; m < 4; ++m)
      af[m] = *(const bf16x8*)(&lA[(wr * 64 + m * 16 + r15) * 32 + rg * 8]);
#pragma unroll
    for (int n = 0; n < 4; ++n)
      bfr[n] = *(const bf16x8*)(&lB[(wc * 64 + n * 16 + r15) * 32 + rg * 8]);
#pragma unroll
    for (int m = 0; m < 4; ++m)
#pragma unroll
      for (int n = 0; n < 4; ++n)
        acc[m][n] = MFMA16(af[m], bfr[n], acc[m][n]);
  }

  const int row0 = mb * 128 + wr * 64;
  const int col0 = nb * 128 + wc * 64;
#pragma unroll
  for (int m = 0; m < 4; ++m)
#pragma unroll
    for (int n = 0; n < 4; ++n)
#pragma unroll
      for (int j = 0; j < 4; ++j) {
        int r = row0 + m * 16 + rg * 4 + j;
        int c = col0 + n * 16 + r15;
        Cf[(size_t)r * N + c] = acc[m][n][j] + bias[c];
      }
}

// ---------------- V transpose: Vtmp [B*T][D] -> Vt [B,H,HD,T] ----------------
__global__ __launch_bounds__(256) void k_vtrans(const __bf16* __restrict__ Vtmp,
                                                __bf16* __restrict__ Vt) {
  __shared__ __bf16 tile[64][72];
  const int bh = blockIdx.y;
  const int b = bh >> 4, h = bh & 15;
  const int t0 = blockIdx.x * 64;
  const int tid = threadIdx.x;
#pragma unroll
  for (int i = 0; i < 2; ++i) {
    int e = tid + i * 256;
    int tr = e >> 3, c8 = (e & 7) * 8;
    bf16x8 v = *(const bf16x8*)(Vtmp + (size_t)(b * T_ + t0 + tr) * D_ + h * HD_ + c8);
    *(bf16x8*)(&tile[tr][c8]) = v;
  }
  __syncthreads();
  const int hr = tid >> 2, tc0 = (tid & 3) * 16;
#pragma unroll
  for (int half = 0; half < 2; ++half) {
    bf16x8 o;
#pragma unroll
    for (int i = 0; i < 8; ++i) o[i] = tile[tc0 + half * 8 + i][hr];
    *(bf16x8*)(Vt + ((size_t)bh * HD_ + hr) * T_ + t0 + tc0 + half * 8) = o;
  }
}

// ---------------- flash attention (causal), 4-wave block, LDS-staged K/V ----------------
// (unchanged from round 4 — proven at 88 us)
__global__ __launch_bounds__(256) void k_attn(const __bf16* __restrict__ Qb,
                                              const __bf16* __restrict__ Kb,
                                              const __bf16* __restrict__ Vt,
                                              __bf16* __restrict__ Obuf) {
  __shared__ __bf16 lK[2][64 * 64];
  __shared__ __bf16 lV[2][64 * 64];
  const int tid = threadIdx.x;
  const int lane = tid & 63, w = tid >> 6;
  const int l31 = lane & 31, hi = lane >> 5;
  const int bh = blockIdx.y;
  const int b = bh >> 4, h = bh & 15;
  const __bf16* Qh = Qb + (size_t)bh * T_ * HD_;
  const __bf16* Kh = Kb + (size_t)bh * T_ * HD_;
  const __bf16* Vh = Vt + (size_t)bh * HD_ * T_;

  const int sRow0 = tid >> 3, sCc0 = tid & 7;
  const int sRow1 = (tid + 256) >> 3, sCc1 = (tid + 256) & 7;
  const int sSw0 = (sCc0 ^ (sRow0 & 7)) * 8;
  const int sSw1 = (sCc1 ^ (sRow1 & 7)) * 8;

  auto STAGE = [&](int bufi, int kv0) {
#ifdef HAVE_GLDS
    GLDS16(Kh + (size_t)(kv0 + sRow0) * HD_ + sSw0, &lK[bufi][tid * 8]);
    GLDS16(Kh + (size_t)(kv0 + sRow1) * HD_ + sSw1, &lK[bufi][(tid + 256) * 8]);
    GLDS16(Vh + (size_t)sRow0 * T_ + kv0 + sSw0, &lV[bufi][tid * 8]);
    GLDS16(Vh + (size_t)sRow1 * T_ + kv0 + sSw1, &lV[bufi][(tid + 256) * 8]);
#else
    bf16x8 k0 = *(const bf16x8*)(Kh + (size_t)(kv0 + sRow0) * HD_ + sSw0);
    bf16x8 k1 = *(const bf16x8*)(Kh + (size_t)(kv0 + sRow1) * HD_ + sSw1);
    bf16x8 v0 = *(const bf16x8*)(Vh + (size_t)sRow0 * T_ + kv0 + sSw0);
    bf16x8 v1 = *(const bf16x8*)(Vh + (size_t)sRow1 * T_ + kv0 + sSw1);
    *(bf16x8*)(&lK[bufi][tid * 8]) = k0;
    *(bf16x8*)(&lK[bufi][(tid + 256) * 8]) = k1;
    *(bf16x8*)(&lV[bufi][tid * 8]) = v0;
    *(bf16x8*)(&lV[bufi][(tid + 256) * 8]) = v1;
#endif
  };

  int buf = 0;
  STAGE(0, 0);

  auto process_half = [&](int s, int nst, bool hasNext) {
    const int q0w = s * 128 + w * 32;
    bf16x8 qf[4];
#pragma unroll
    for (int ks = 0; ks < 4; ++ks)
      qf[ks] = *(const bf16x8*)(Qh + (size_t)(q0w + l31) * HD_ + ks * 16 + hi * 8);

    f32x16 o0, o1;
#pragma unroll
    for (int i = 0; i < 16; ++i) { o0[i] = 0.f; o1[i] = 0.f; }
    float mrun = -INFINITY, lrun = 0.f;

    for (int i = 0; i < nst; ++i) {
      const int kv0 = i * 64;
      if (i + 1 < nst) STAGE(buf ^ 1, (i + 1) * 64);
      else if (hasNext) STAGE(buf ^ 1, 0);

      if (kv0 <= q0w + 31) {
        const bool masked = (kv0 + 63) > q0w;
        bf16x8 kf[2][4];
#pragma unroll
        for (int seg = 0; seg < 2; ++seg)
#pragma unroll
          for (int ks = 0; ks < 4; ++ks)
            kf[seg][ks] = *(const bf16x8*)(&lK[buf][(seg * 32 + l31) * 64 +
                                                   (((ks * 2 + hi) ^ (l31 & 7)) * 8)]);
        f32x16 s0, s1;
#pragma unroll
        for (int r = 0; r < 16; ++r) { s0[r] = 0.f; s1[r] = 0.f; }
#pragma unroll
        for (int ks = 0; ks < 4; ++ks) s0 = MFMA32(kf[0][ks], qf[ks], s0);
#pragma unroll
        for (int ks = 0; ks < 4; ++ks) s1 = MFMA32(kf[1][ks], qf[ks], s1);

        if (masked) {
#pragma unroll
          for (int r = 0; r < 16; ++r) {
            int rr = (r & 3) + 8 * (r >> 2) + 4 * hi;
            if (kv0 + rr > q0w + l31) s0[r] = -INFINITY;
            if (kv0 + 32 + rr > q0w + l31) s1[r] = -INFINITY;
          }
        }
        float pmax = -INFINITY;
#pragma unroll
        for (int r = 0; r < 16; ++r) pmax = fmaxf(pmax, fmaxf(s0[r], s1[r]));
        pmax = fmaxf(pmax, __shfl_xor(pmax, 32, 64));

        if (__any(pmax > mrun + 8.0f)) {
          float mnew = fmaxf(mrun, pmax);
          float sc = EXP2(mrun - mnew);
#pragma unroll
          for (int r = 0; r < 16; ++r) {
            int rr = (r & 3) + 8 * (r >> 2) + 4 * hi;
            float scr = __shfl(sc, rr, 64);
            o0[r] *= scr; o1[r] *= scr;
          }
          lrun *= sc;
          mrun = mnew;
        }
        float rs = 0.f;
#pragma unroll
        for (int r = 0; r < 16; ++r) {
          s0[r] = EXP2(s0[r] - mrun); s1[r] = EXP2(s1[r] - mrun);
          rs += s0[r] + s1[r];
        }
        rs += __shfl_xor(rs, 32, 64);
        lrun += rs;

        bf16x8 vf[2][4];
#pragma unroll
        for (int dh = 0; dh < 2; ++dh)
#pragma unroll
          for (int ks = 0; ks < 4; ++ks)
            vf[dh][ks] = *(const bf16x8*)(&lV[buf][(dh * 32 + l31) * 64 +
                                                   (((ks * 2 + hi) ^ (l31 & 7)) * 8)]);

#pragma unroll
        for (int ks = 0; ks < 4; ++ks) {
          const f32x16& sv = (ks < 2) ? s0 : s1;
          const int off = (ks & 1) * 8;
          uint32_t w0 = pack2bf(sv[off + 0], sv[off + 1]);
          uint32_t w1 = pack2bf(sv[off + 2], sv[off + 3]);
          uint32_t w2 = pack2bf(sv[off + 4], sv[off + 5]);
          uint32_t w3 = pack2bf(sv[off + 6], sv[off + 7]);
          uint32_t sx = hi ? w0 : w2;
          uint32_t sy = hi ? w1 : w3;
          uint32_t px = (uint32_t)__shfl_xor((int)sx, 32, 64);
          uint32_t py = (uint32_t)__shfl_xor((int)sy, 32, 64);
          union { uint32_t u[4]; bf16x8 v; } pa;
          pa.u[0] = hi ? px : w0;
          pa.u[1] = hi ? py : w1;
          pa.u[2] = hi ? w2 : px;
          pa.u[3] = hi ? w3 : py;
          o0 = MFMA32(pa.v, vf[0][ks], o0);
          o1 = MFMA32(pa.v, vf[1][ks], o1);
        }
      }
      __syncthreads();
      buf ^= 1;
    }

#pragma unroll
    for (int r = 0; r < 16; ++r) {
      int rr = (r & 3) + 8 * (r >> 2) + 4 * hi;
      float inv = 1.0f / __shfl(lrun, rr, 64);
      int row = q0w + rr;
      __bf16* op = Obuf + (size_t)(b * T_ + row) * D_ + h * HD_ + l31;
      op[0]  = (__bf16)(o0[r] * inv);
      op[32] = (__bf16)(o1[r] * inv);
    }
  };

  const int sA = 15 - blockIdx.x;
  const int sB = blockIdx.x;
  __syncthreads();
  process_half(sA, 2 * sA + 2, true);
  process_half(sB, 2 * sB + 2, false);
}

// ---------------- launcher ----------------
extern "C" void kernel_launch(void* const* d_in, const int* in_sizes, int n_in,
                              void* d_out, int out_size, void* d_ws, size_t ws_size,
                              hipStream_t stream) {
  const float* x      = (const float*)d_in[0];
  const float* W_qkv  = (const float*)d_in[1];
  const float* b_qkv  = (const float*)d_in[2];
  const float* W_proj = (const float*)d_in[3];
  const float* b_proj = (const float*)d_in[4];
  float* out = (float*)d_out;

  char* ws = (char*)d_ws;
  size_t o = 0;
  __bf16* xb     = (__bf16*)(ws + o); o += (size_t)M_ * D_ * 2;
  __bf16* wqkvt  = (__bf16*)(ws + o); o += (size_t)NQKV_ * D_ * 2;
  __bf16* wprojt = (__bf16*)(ws + o); o += (size_t)D_ * D_ * 2;
  __bf16* Qb     = (__bf16*)(ws + o); o += (size_t)M_ * D_ * 2;
  __bf16* Kb     = (__bf16*)(ws + o); o += (size_t)M_ * D_ * 2;
  __bf16* Vtmp   = (__bf16*)(ws + o); o += (size_t)M_ * D_ * 2;
  __bf16* Vt     = (__bf16*)(ws + o); o += (size_t)M_ * D_ * 2;
  __bf16* Obuf   = (__bf16*)(ws + o); o += (size_t)M_ * D_ * 2;
  (void)ws_size; (void)in_sizes; (void)n_in; (void)out_size;

  k_cvt_bf16<<<(M_ * D_ / 4 + 255) / 256, 256, 0, stream>>>((const float4*)x, (bf16x4*)xb, M_ * D_ / 4);
  k_transpose_cvt<<<dim3(NQKV_ / 64, D_ / 64), 256, 0, stream>>>(W_qkv, wqkvt, D_, NQKV_);
  k_transpose_cvt<<<dim3(D_ / 64, D_ / 64), 256, 0, stream>>>(W_proj, wprojt, D_, D_);
  k_gemm256_qkv<<<dim3(NQKV_ / 256, M_ / 256), 512, 0, stream>>>(xb, wqkvt, b_qkv, Qb, Kb, Vtmp);
  k_vtrans<<<dim3(T_ / 64, B_ * H_), 256, 0, stream>>>(Vtmp, Vt);
  k_attn<<<dim3(8, B_ * H_), 256, 0, stream>>>(Qb, Kb, Vt, Obuf);
  k_gemm_proj<<<dim3(D_ / 128, M_ / 128), 256, 0, stream>>>(Obuf, wprojt, b_proj, out, D_, D_);
}